// Round 4
// baseline (2492.417 us; speedup 1.0000x reference)
//
#include <hip/hip_runtime.h>
#include <hip/hip_bf16.h>

typedef short bf16x8 __attribute__((ext_vector_type(8)));
typedef float f32x4 __attribute__((ext_vector_type(4)));

#define MFMA16(A,B,C) __builtin_amdgcn_mfma_f32_16x16x32_bf16(A,B,C,0,0,0)

static __device__ __forceinline__ unsigned short f2bf(float f) {
  unsigned int u = __float_as_uint(f);
  u += 0x7fffu + ((u >> 16) & 1u);        // round-to-nearest-even
  return (unsigned short)(u >> 16);
}

#define SWZ(row, byte) ((byte) ^ (((row) & 7) << 4))
#define OFF_XW 0
#define OFF_QK 32768
#define OFF_VT 65536
#define LDS_TOTAL 81920

#define NQKV 196608   // 768*256
#define NPROJ 65536   // 256*256
#define OBUF_OFF 524288                    // bytes into d_ws where O lives
#define OBUF_BYTES ((size_t)8192 * 32768)  // [8192 win][2 quad][64 tok][128 ch] bf16
#define WS_NEED (OBUF_OFF + OBUF_BYTES)

__global__ void convert_w_kernel(const float* __restrict__ qkv_w,
                                 const float* __restrict__ proj_w,
                                 ushort* __restrict__ wsb) {
  int i = blockIdx.x * 256 + threadIdx.x;
  if (i < NQKV) wsb[i] = f2bf(qkv_w[i]);
  else if (i < NQKV + NPROJ) wsb[i] = f2bf(proj_w[i - NQKV]);
}

// ============================ split path: kernel A ============================
// QKV + window attention. No proj accumulator -> peak accum pressure is the
// QKV acc[4][3] (48 f32). (512,4) => <=128 regs/wave => 4 waves/SIMD; LDS 80 KB
// => 2 blocks/CU.
__global__ __launch_bounds__(512, 4)
void swin_attn_kernel(const float* __restrict__ x,
                      const ushort* __restrict__ qkvw,    // [768][256] bf16
                      const float* __restrict__ rel_bias, // [8][64][64] f32
                      char* __restrict__ obuf) {          // [8192][2][64][128] bf16
  extern __shared__ char smem[];

  const int wid = blockIdx.x;
  const int bb_ = wid >> 10;
  const int wy  = (wid >> 5) & 31;
  const int wx  = wid & 31;
  const int tid  = threadIdx.x;
  const int wave = tid >> 6;
  const int lane = tid & 63;
  const int l16  = lane & 15;
  const int lq   = lane >> 4;

  // ---- stage x window [64 tok][256 ch] as bf16 (zero-fill padding)
  #pragma unroll
  for (int it = 0; it < 8; ++it) {
    const int t  = it * 8 + wave;
    const int gr = wy * 8 + (t >> 3);
    const int gc = wx * 8 + (t & 7);
    float4 v = make_float4(0.f, 0.f, 0.f, 0.f);
    if (gr < 250 && gc < 250)
      v = *(const float4*)(x + ((size_t)bb_ * 62500 + (size_t)gr * 250 + gc) * 256 + lane * 4);
    ushort4 bv;
    bv.x = f2bf(v.x); bv.y = f2bf(v.y); bv.z = f2bf(v.z); bv.w = f2bf(v.w);
    *(ushort4*)(smem + OFF_XW + t * 512 + SWZ(t, lane * 8)) = bv;
  }

  const int hl = wave >> 1;
  const int mh = wave & 1;
  const float scale = 0.17677669529663687f;  // 32^-0.5

  for (int quad = 0; quad < 2; ++quad) {
    const int H0 = quad * 4;
    __syncthreads();  // (a) xw ready / prev quad O-store reads of OFF_VT done

    // ---- QKV GEMM: [64,256] x [256, 4heads*96]
    f32x4 acc[4][3];
    #pragma unroll
    for (int m = 0; m < 4; ++m)
      #pragma unroll
      for (int j = 0; j < 3; ++j)
        acc[m][j] = f32x4{0.f, 0.f, 0.f, 0.f};

    const ushort* bp[3];
    #pragma unroll
    for (int j = 0; j < 3; ++j) {
      const int n = wave * 3 + j;
      const int ty = n >> 3, rem = n & 7;
      const int wrow = ty * 256 + (H0 + (rem >> 1)) * 32 + (rem & 1) * 16 + l16;
      bp[j] = qkvw + (size_t)wrow * 256 + lq * 8;
    }
    #pragma unroll
    for (int kk = 0; kk < 8; ++kk) {
      bf16x8 af[4];
      #pragma unroll
      for (int m = 0; m < 4; ++m) {
        const int r = m * 16 + l16;
        af[m] = *(const bf16x8*)(smem + OFF_XW + r * 512 + SWZ(r, kk * 64 + lq * 16));
      }
      #pragma unroll
      for (int j = 0; j < 3; ++j) {
        bf16x8 bf = *(const bf16x8*)(bp[j] + kk * 32);
        #pragma unroll
        for (int m = 0; m < 4; ++m)
          acc[m][j] = MFMA16(af[m], bf, acc[m][j]);
      }
    }
    // scatter QKV to LDS (q pre-scaled; v transposed)
    #pragma unroll
    for (int j = 0; j < 3; ++j) {
      const int n = wave * 3 + j;
      const int ty = n >> 3, rem = n & 7;
      const int hh = rem >> 1, half = rem & 1;
      const int d = half * 16 + l16;
      if (ty == 2) {
        #pragma unroll
        for (int m = 0; m < 4; ++m) {
          ushort4 pk;
          pk.x = f2bf(acc[m][j][0]); pk.y = f2bf(acc[m][j][1]);
          pk.z = f2bf(acc[m][j][2]); pk.w = f2bf(acc[m][j][3]);
          const int tok0 = m * 16 + lq * 4;
          *(ushort4*)(smem + OFF_VT + (hh * 32 + d) * 128 + SWZ(d, tok0 * 2)) = pk;
        }
      } else {
        #pragma unroll
        for (int m = 0; m < 4; ++m)
          #pragma unroll
          for (int rr = 0; rr < 4; ++rr) {
            const int tok = m * 16 + lq * 4 + rr;
            const float v = acc[m][j][rr];
            if (ty == 0)
              *(ushort*)(smem + OFF_QK + (hh * 64 + tok) * 128 + SWZ(tok, d * 2)) = f2bf(v * scale);
            else
              *(ushort*)(smem + OFF_QK + (hh * 64 + tok) * 128 + SWZ(tok, 64 + d * 2)) = f2bf(v);
          }
      }
    }
    __syncthreads();  // (b) q/k/vT ready

    // ---- S = Qs*K^T (wave owns head hl, rows [mh*32,+32))
    f32x4 s[2][4];
    {
      bf16x8 qf[2];
      #pragma unroll
      for (int mt = 0; mt < 2; ++mt) {
        const int r = mh * 32 + mt * 16 + l16;
        qf[mt] = *(const bf16x8*)(smem + OFF_QK + (hl * 64 + r) * 128 + SWZ(r, lq * 16));
      }
      #pragma unroll
      for (int nt = 0; nt < 4; ++nt) {
        const int r = nt * 16 + l16;
        bf16x8 kf = *(const bf16x8*)(smem + OFF_QK + (hl * 64 + r) * 128 + SWZ(r, 64 + lq * 16));
        #pragma unroll
        for (int mt = 0; mt < 2; ++mt)
          s[mt][nt] = MFMA16(qf[mt], kf, (f32x4{0.f, 0.f, 0.f, 0.f}));
      }
    }
    __syncthreads();  // (b2) q/k reads done -> P overlays q/k

    // ---- softmax
    const float* biasb = rel_bias + (size_t)(H0 + hl) * 4096;
    float rcp_[2][4];
    #pragma unroll
    for (int mt = 0; mt < 2; ++mt) {
      #pragma unroll
      for (int rr = 0; rr < 4; ++rr) {
        const int qrow = mh * 32 + mt * 16 + lq * 4 + rr;
        float vmax = -1e30f;
        #pragma unroll
        for (int nt = 0; nt < 4; ++nt) {
          float v = s[mt][nt][rr] + biasb[qrow * 64 + nt * 16 + l16];
          s[mt][nt][rr] = v;
          vmax = fmaxf(vmax, v);
        }
        vmax = fmaxf(vmax, __shfl_xor(vmax, 1));
        vmax = fmaxf(vmax, __shfl_xor(vmax, 2));
        vmax = fmaxf(vmax, __shfl_xor(vmax, 4));
        vmax = fmaxf(vmax, __shfl_xor(vmax, 8));
        float ssum = 0.f;
        #pragma unroll
        for (int nt = 0; nt < 4; ++nt) {
          float e = __expf(s[mt][nt][rr] - vmax);
          ssum += e;
          *(ushort*)(smem + OFF_QK + (hl * 64 + qrow) * 128 + SWZ(qrow, (nt * 16 + l16) * 2)) = f2bf(e);
        }
        ssum += __shfl_xor(ssum, 1);
        ssum += __shfl_xor(ssum, 2);
        ssum += __shfl_xor(ssum, 4);
        ssum += __shfl_xor(ssum, 8);
        rcp_[mt][rr] = 1.f / ssum;
      }
    }

    // ---- PV
    f32x4 o[2][2];
    #pragma unroll
    for (int mt = 0; mt < 2; ++mt)
      #pragma unroll
      for (int nt = 0; nt < 2; ++nt)
        o[mt][nt] = f32x4{0.f, 0.f, 0.f, 0.f};
    #pragma unroll
    for (int kk = 0; kk < 2; ++kk) {
      bf16x8 pf[2];
      #pragma unroll
      for (int mt = 0; mt < 2; ++mt) {
        const int r = mh * 32 + mt * 16 + l16;
        pf[mt] = *(const bf16x8*)(smem + OFF_QK + (hl * 64 + r) * 128 + SWZ(r, kk * 64 + lq * 16));
      }
      #pragma unroll
      for (int nt = 0; nt < 2; ++nt) {
        const int r = nt * 16 + l16;
        bf16x8 vf = *(const bf16x8*)(smem + OFF_VT + (hl * 32 + r) * 128 + SWZ(r, kk * 64 + lq * 16));
        #pragma unroll
        for (int mt = 0; mt < 2; ++mt)
          o[mt][nt] = MFMA16(pf[mt], vf, o[mt][nt]);
      }
    }
    __syncthreads();  // (c1) vT reads done -> O tile overlays vt

    #pragma unroll
    for (int mt = 0; mt < 2; ++mt)
      #pragma unroll
      for (int nt = 0; nt < 2; ++nt)
        #pragma unroll
        for (int rr = 0; rr < 4; ++rr) {
          const int tok = mh * 32 + mt * 16 + lq * 4 + rr;
          const int col = hl * 32 + nt * 16 + l16;  // local channel in quad
          *(ushort*)(smem + OFF_VT + tok * 256 + SWZ(tok, col * 2)) = f2bf(o[mt][nt][rr] * rcp_[mt][rr]);
        }
    __syncthreads();  // (c2) O tile ready

    // ---- coalesced O store: [64 tok][128 ch] bf16 -> obuf
    char* od = obuf + (size_t)wid * 32768 + quad * 16384;
    #pragma unroll
    for (int i = 0; i < 2; ++i) {
      const int idx = i * 512 + tid;
      const int row = idx >> 4, c16 = idx & 15;
      bf16x8 v = *(const bf16x8*)(smem + OFF_VT + row * 256 + SWZ(row, c16 * 16));
      *(bf16x8*)(od + row * 256 + c16 * 16) = v;
    }
  }
}

// ============================ split path: kernel B ============================
// out = O @ projW^T + b, with unpad scatter. Streaming GEMM, no LDS.
__global__ __launch_bounds__(256, 4)
void proj_kernel(const char* __restrict__ obuf,     // [8192][2][64][128] bf16
                 const ushort* __restrict__ projw,  // [256][256] bf16
                 const float* __restrict__ proj_b,
                 float* __restrict__ out) {
  const int wid = blockIdx.x;
  const int bb_ = wid >> 10;
  const int wy  = (wid >> 5) & 31;
  const int wx  = wid & 31;
  const int tid  = threadIdx.x;
  const int wave = tid >> 6;           // 0..3, owns cols [wave*64, +64)
  const int lane = tid & 63;
  const int l16  = lane & 15;
  const int lq   = lane >> 4;
  const char* ob = obuf + (size_t)wid * 32768;

  #pragma unroll
  for (int half = 0; half < 2; ++half) {
    f32x4 acc[4][2];
    #pragma unroll
    for (int m = 0; m < 4; ++m)
      #pragma unroll
      for (int nt = 0; nt < 2; ++nt)
        acc[m][nt] = f32x4{0.f, 0.f, 0.f, 0.f};

    #pragma unroll
    for (int quad = 0; quad < 2; ++quad)
      #pragma unroll
      for (int kk = 0; kk < 4; ++kk) {
        bf16x8 af[4];
        #pragma unroll
        for (int m = 0; m < 4; ++m)
          af[m] = *(const bf16x8*)(ob + quad * 16384 + (m * 16 + l16) * 256 + kk * 64 + lq * 16);
        #pragma unroll
        for (int nt = 0; nt < 2; ++nt) {
          const int c = wave * 64 + half * 32 + nt * 16 + l16;
          bf16x8 bfr = *(const bf16x8*)(projw + (size_t)c * 256 + quad * 128 + kk * 32 + lq * 8);
          #pragma unroll
          for (int m = 0; m < 4; ++m)
            acc[m][nt] = MFMA16(af[m], bfr, acc[m][nt]);
        }
      }

    #pragma unroll
    for (int nt = 0; nt < 2; ++nt) {
      const int col = wave * 64 + half * 32 + nt * 16 + l16;
      const float pb = proj_b[col];
      #pragma unroll
      for (int m = 0; m < 4; ++m)
        #pragma unroll
        for (int rr = 0; rr < 4; ++rr) {
          const int tok = m * 16 + lq * 4 + rr;
          const int gr = wy * 8 + (tok >> 3);
          const int gc = wx * 8 + (tok & 7);
          if (gr < 250 && gc < 250)
            out[((size_t)bb_ * 62500 + (size_t)gr * 250 + gc) * 256 + col] = acc[m][nt][rr] + pb;
        }
    }
  }
}

// ===================== fallback: Round-3 fused kernel (known-pass) ============
__global__ __launch_bounds__(512, 2)
void swin_fused_kernel(const float* __restrict__ x,
                       const ushort* __restrict__ qkvw,
                       const ushort* __restrict__ projw,
                       const float* __restrict__ proj_b,
                       const float* __restrict__ rel_bias,
                       float* __restrict__ out) {
  extern __shared__ char smem[];
  const int wid = blockIdx.x;
  const int bb_ = wid >> 10;
  const int wy  = (wid >> 5) & 31;
  const int wx  = wid & 31;
  const int tid  = threadIdx.x;
  const int wave = tid >> 6;
  const int lane = tid & 63;
  const int l16  = lane & 15;
  const int lq   = lane >> 4;

  #pragma unroll
  for (int it = 0; it < 8; ++it) {
    const int t  = it * 8 + wave;
    const int gr = wy * 8 + (t >> 3);
    const int gc = wx * 8 + (t & 7);
    float4 v = make_float4(0.f, 0.f, 0.f, 0.f);
    if (gr < 250 && gc < 250)
      v = *(const float4*)(x + ((size_t)bb_ * 62500 + (size_t)gr * 250 + gc) * 256 + lane * 4);
    ushort4 bv;
    bv.x = f2bf(v.x); bv.y = f2bf(v.y); bv.z = f2bf(v.z); bv.w = f2bf(v.w);
    *(ushort4*)(smem + OFF_XW + t * 512 + SWZ(t, lane * 8)) = bv;
  }

  f32x4 oacc[4][2];
  #pragma unroll
  for (int m = 0; m < 4; ++m)
    #pragma unroll
    for (int n = 0; n < 2; ++n)
      oacc[m][n] = f32x4{0.f, 0.f, 0.f, 0.f};

  const int hl = wave >> 1;
  const int mh = wave & 1;
  const float scale = 0.17677669529663687f;

  for (int quad = 0; quad < 2; ++quad) {
    const int H0 = quad * 4;
    __syncthreads();
    f32x4 acc[4][3];
    #pragma unroll
    for (int m = 0; m < 4; ++m)
      #pragma unroll
      for (int j = 0; j < 3; ++j)
        acc[m][j] = f32x4{0.f, 0.f, 0.f, 0.f};
    const ushort* bp[3];
    #pragma unroll
    for (int j = 0; j < 3; ++j) {
      const int n = wave * 3 + j;
      const int ty = n >> 3, rem = n & 7;
      const int wrow = ty * 256 + (H0 + (rem >> 1)) * 32 + (rem & 1) * 16 + l16;
      bp[j] = qkvw + (size_t)wrow * 256 + lq * 8;
    }
    #pragma unroll
    for (int kk = 0; kk < 8; ++kk) {
      bf16x8 af[4];
      #pragma unroll
      for (int m = 0; m < 4; ++m) {
        const int r = m * 16 + l16;
        af[m] = *(const bf16x8*)(smem + OFF_XW + r * 512 + SWZ(r, kk * 64 + lq * 16));
      }
      #pragma unroll
      for (int j = 0; j < 3; ++j) {
        bf16x8 bf = *(const bf16x8*)(bp[j] + kk * 32);
        #pragma unroll
        for (int m = 0; m < 4; ++m)
          acc[m][j] = MFMA16(af[m], bf, acc[m][j]);
      }
    }
    #pragma unroll
    for (int j = 0; j < 3; ++j) {
      const int n = wave * 3 + j;
      const int ty = n >> 3, rem = n & 7;
      const int hh = rem >> 1, half = rem & 1;
      const int d = half * 16 + l16;
      if (ty == 2) {
        #pragma unroll
        for (int m = 0; m < 4; ++m) {
          ushort4 pk;
          pk.x = f2bf(acc[m][j][0]); pk.y = f2bf(acc[m][j][1]);
          pk.z = f2bf(acc[m][j][2]); pk.w = f2bf(acc[m][j][3]);
          const int tok0 = m * 16 + lq * 4;
          *(ushort4*)(smem + OFF_VT + (hh * 32 + d) * 128 + SWZ(d, tok0 * 2)) = pk;
        }
      } else {
        #pragma unroll
        for (int m = 0; m < 4; ++m)
          #pragma unroll
          for (int rr = 0; rr < 4; ++rr) {
            const int tok = m * 16 + lq * 4 + rr;
            const float v = acc[m][j][rr];
            if (ty == 0)
              *(ushort*)(smem + OFF_QK + (hh * 64 + tok) * 128 + SWZ(tok, d * 2)) = f2bf(v * scale);
            else
              *(ushort*)(smem + OFF_QK + (hh * 64 + tok) * 128 + SWZ(tok, 64 + d * 2)) = f2bf(v);
          }
      }
    }
    __syncthreads();
    f32x4 s[2][4];
    {
      bf16x8 qf[2];
      #pragma unroll
      for (int mt = 0; mt < 2; ++mt) {
        const int r = mh * 32 + mt * 16 + l16;
        qf[mt] = *(const bf16x8*)(smem + OFF_QK + (hl * 64 + r) * 128 + SWZ(r, lq * 16));
      }
      #pragma unroll
      for (int nt = 0; nt < 4; ++nt) {
        const int r = nt * 16 + l16;
        bf16x8 kf = *(const bf16x8*)(smem + OFF_QK + (hl * 64 + r) * 128 + SWZ(r, 64 + lq * 16));
        #pragma unroll
        for (int mt = 0; mt < 2; ++mt)
          s[mt][nt] = MFMA16(qf[mt], kf, (f32x4{0.f, 0.f, 0.f, 0.f}));
      }
    }
    __syncthreads();
    const float* biasb = rel_bias + (size_t)(H0 + hl) * 4096;
    float rcp_[2][4];
    #pragma unroll
    for (int mt = 0; mt < 2; ++mt) {
      #pragma unroll
      for (int rr = 0; rr < 4; ++rr) {
        const int qrow = mh * 32 + mt * 16 + lq * 4 + rr;
        float vmax = -1e30f;
        #pragma unroll
        for (int nt = 0; nt < 4; ++nt) {
          float v = s[mt][nt][rr] + biasb[qrow * 64 + nt * 16 + l16];
          s[mt][nt][rr] = v;
          vmax = fmaxf(vmax, v);
        }
        vmax = fmaxf(vmax, __shfl_xor(vmax, 1));
        vmax = fmaxf(vmax, __shfl_xor(vmax, 2));
        vmax = fmaxf(vmax, __shfl_xor(vmax, 4));
        vmax = fmaxf(vmax, __shfl_xor(vmax, 8));
        float ssum = 0.f;
        #pragma unroll
        for (int nt = 0; nt < 4; ++nt) {
          float e = __expf(s[mt][nt][rr] - vmax);
          ssum += e;
          *(ushort*)(smem + OFF_QK + (hl * 64 + qrow) * 128 + SWZ(qrow, (nt * 16 + l16) * 2)) = f2bf(e);
        }
        ssum += __shfl_xor(ssum, 1);
        ssum += __shfl_xor(ssum, 2);
        ssum += __shfl_xor(ssum, 4);
        ssum += __shfl_xor(ssum, 8);
        rcp_[mt][rr] = 1.f / ssum;
      }
    }
    f32x4 o[2][2];
    #pragma unroll
    for (int mt = 0; mt < 2; ++mt)
      #pragma unroll
      for (int nt = 0; nt < 2; ++nt)
        o[mt][nt] = f32x4{0.f, 0.f, 0.f, 0.f};
    #pragma unroll
    for (int kk = 0; kk < 2; ++kk) {
      bf16x8 pf[2];
      #pragma unroll
      for (int mt = 0; mt < 2; ++mt) {
        const int r = mh * 32 + mt * 16 + l16;
        pf[mt] = *(const bf16x8*)(smem + OFF_QK + (hl * 64 + r) * 128 + SWZ(r, kk * 64 + lq * 16));
      }
      #pragma unroll
      for (int nt = 0; nt < 2; ++nt) {
        const int r = nt * 16 + l16;
        bf16x8 vf = *(const bf16x8*)(smem + OFF_VT + (hl * 32 + r) * 128 + SWZ(r, kk * 64 + lq * 16));
        #pragma unroll
        for (int mt = 0; mt < 2; ++mt)
          o[mt][nt] = MFMA16(pf[mt], vf, o[mt][nt]);
      }
    }
    __syncthreads();
    #pragma unroll
    for (int mt = 0; mt < 2; ++mt)
      #pragma unroll
      for (int nt = 0; nt < 2; ++nt)
        #pragma unroll
        for (int rr = 0; rr < 4; ++rr) {
          const int tok = mh * 32 + mt * 16 + lq * 4 + rr;
          const int col = hl * 32 + nt * 16 + l16;
          *(ushort*)(smem + OFF_VT + tok * 256 + SWZ(tok, col * 2)) = f2bf(o[mt][nt][rr] * rcp_[mt][rr]);
        }
    __syncthreads();
    #pragma unroll
    for (int kk = 0; kk < 4; ++kk) {
      bf16x8 af[4];
      #pragma unroll
      for (int m = 0; m < 4; ++m) {
        const int r = m * 16 + l16;
        af[m] = *(const bf16x8*)(smem + OFF_VT + r * 256 + SWZ(r, kk * 64 + lq * 16));
      }
      #pragma unroll
      for (int nt = 0; nt < 2; ++nt) {
        const int c = wave * 32 + nt * 16 + l16;
        bf16x8 bfr = *(const bf16x8*)(projw + (size_t)c * 256 + quad * 128 + kk * 32 + lq * 8);
        #pragma unroll
        for (int m = 0; m < 4; ++m)
          oacc[m][nt] = MFMA16(af[m], bfr, oacc[m][nt]);
      }
    }
  }

  __syncthreads();
  #pragma unroll
  for (int nt = 0; nt < 2; ++nt) {
    const int col = wave * 32 + nt * 16 + l16;
    const float pb = proj_b[col];
    #pragma unroll
    for (int m = 0; m < 4; ++m)
      #pragma unroll
      for (int rr = 0; rr < 4; ++rr) {
        const int row = m * 16 + lq * 4 + rr;
        *(float*)(smem + row * 1024 + SWZ(row, col * 4)) = oacc[m][nt][rr] + pb;
      }
  }
  __syncthreads();
  #pragma unroll
  for (int it = 0; it < 8; ++it) {
    const int t  = it * 8 + wave;
    const int gr = wy * 8 + (t >> 3);
    const int gc = wx * 8 + (t & 7);
    if (gr < 250 && gc < 250) {
      float4 v = *(const float4*)(smem + t * 1024 + SWZ(t, lane * 16));
      *(float4*)(out + ((size_t)bb_ * 62500 + (size_t)gr * 250 + gc) * 256 + lane * 4) = v;
    }
  }
}

extern "C" void kernel_launch(void* const* d_in, const int* in_sizes, int n_in,
                              void* d_out, int out_size, void* d_ws, size_t ws_size,
                              hipStream_t stream) {
  const float* x        = (const float*)d_in[0];
  const float* qkv_w    = (const float*)d_in[1];
  const float* proj_w   = (const float*)d_in[2];
  const float* proj_b   = (const float*)d_in[3];
  const float* rel_bias = (const float*)d_in[4];
  float* out = (float*)d_out;
  ushort* wsb = (ushort*)d_ws;

  (void)in_sizes; (void)n_in; (void)out_size;

  hipFuncSetAttribute((const void*)swin_attn_kernel,
                      hipFuncAttributeMaxDynamicSharedMemorySize, LDS_TOTAL);
  hipFuncSetAttribute((const void*)swin_fused_kernel,
                      hipFuncAttributeMaxDynamicSharedMemorySize, LDS_TOTAL);

  convert_w_kernel<<<1024, 256, 0, stream>>>(qkv_w, proj_w, wsb);

  if (ws_size >= WS_NEED) {
    char* obuf = (char*)d_ws + OBUF_OFF;
    swin_attn_kernel<<<8192, 512, LDS_TOTAL, stream>>>(x, wsb, rel_bias, obuf);
    proj_kernel<<<8192, 256, 0, stream>>>(obuf, wsb + NQKV, proj_b, out);
  } else {
    swin_fused_kernel<<<8192, 512, LDS_TOTAL, stream>>>(x, wsb, wsb + NQKV, proj_b,
                                                        rel_bias, out);
  }
}

// Round 5
// 1764.335 us; speedup vs baseline: 1.4127x; 1.4127x over previous
//
#include <hip/hip_runtime.h>
#include <hip/hip_bf16.h>

typedef short bf16x8 __attribute__((ext_vector_type(8)));
typedef float f32x4 __attribute__((ext_vector_type(4)));

#define MFMA16(A,B,C) __builtin_amdgcn_mfma_f32_16x16x32_bf16(A,B,C,0,0,0)

static __device__ __forceinline__ unsigned short f2bf(float f) {
  unsigned int u = __float_as_uint(f);
  u += 0x7fffu + ((u >> 16) & 1u);        // round-to-nearest-even
  return (unsigned short)(u >> 16);
}

#define SWZ(row, byte) ((byte) ^ (((row) & 7) << 4))
#define OFF_XW 0
#define OFF_QK 32768
#define OFF_VT 65536
#define LDS_TOTAL 81920

#define NQKV 196608   // 768*256
#define NPROJ 65536   // 256*256
#define OBUF_OFF 524288                    // bytes into d_ws where O lives
#define OBUF_BYTES ((size_t)8192 * 32768)  // [8192 win][2 quad][64 tok][128 ch] bf16
#define WS_NEED (OBUF_OFF + OBUF_BYTES)

__global__ void convert_w_kernel(const float* __restrict__ qkv_w,
                                 const float* __restrict__ proj_w,
                                 ushort* __restrict__ wsb) {
  int i = blockIdx.x * 256 + threadIdx.x;
  if (i < NQKV) wsb[i] = f2bf(qkv_w[i]);
  else if (i < NQKV + NPROJ) wsb[i] = f2bf(proj_w[i - NQKV]);
}

// ============================ split path: kernel A ============================
// QKV + window attention.
// EMPIRICAL launch_bounds semantics on this hipcc: arg2 = min BLOCKS/CU.
// (512,4) -> 32 waves/CU -> 64-VGPR cap -> spills (R2: 8.2GB, R4: 5.3GB HBM).
// (512,2) -> 16 waves/CU -> 128-VGPR cap -> no spill (R1: 100 regs).
// Occupancy of 2 blocks/CU is enforced by the 80 KB LDS, not the reg cap.
__global__ __launch_bounds__(512, 2)
void swin_attn_kernel(const float* __restrict__ x,
                      const ushort* __restrict__ qkvw,    // [768][256] bf16
                      const float* __restrict__ rel_bias, // [8][64][64] f32
                      char* __restrict__ obuf) {          // [8192][2][64][128] bf16
  extern __shared__ char smem[];

  const int wid = blockIdx.x;
  const int bb_ = wid >> 10;
  const int wy  = (wid >> 5) & 31;
  const int wx  = wid & 31;
  const int tid  = threadIdx.x;
  const int wave = tid >> 6;
  const int lane = tid & 63;
  const int l16  = lane & 15;
  const int lq   = lane >> 4;

  // ---- stage x window [64 tok][256 ch] as bf16 (zero-fill padding)
  #pragma unroll
  for (int it = 0; it < 8; ++it) {
    const int t  = it * 8 + wave;
    const int gr = wy * 8 + (t >> 3);
    const int gc = wx * 8 + (t & 7);
    float4 v = make_float4(0.f, 0.f, 0.f, 0.f);
    if (gr < 250 && gc < 250)
      v = *(const float4*)(x + ((size_t)bb_ * 62500 + (size_t)gr * 250 + gc) * 256 + lane * 4);
    ushort4 bv;
    bv.x = f2bf(v.x); bv.y = f2bf(v.y); bv.z = f2bf(v.z); bv.w = f2bf(v.w);
    *(ushort4*)(smem + OFF_XW + t * 512 + SWZ(t, lane * 8)) = bv;
  }

  const int hl = wave >> 1;
  const int mh = wave & 1;
  const float scale = 0.17677669529663687f;  // 32^-0.5

  for (int quad = 0; quad < 2; ++quad) {
    const int H0 = quad * 4;
    __syncthreads();  // (a) xw ready / prev quad O-store reads of OFF_VT done

    // ---- QKV GEMM: [64,256] x [256, 4heads*96]
    f32x4 acc[4][3];
    #pragma unroll
    for (int m = 0; m < 4; ++m)
      #pragma unroll
      for (int j = 0; j < 3; ++j)
        acc[m][j] = f32x4{0.f, 0.f, 0.f, 0.f};

    const ushort* bp[3];
    #pragma unroll
    for (int j = 0; j < 3; ++j) {
      const int n = wave * 3 + j;
      const int ty = n >> 3, rem = n & 7;
      const int wrow = ty * 256 + (H0 + (rem >> 1)) * 32 + (rem & 1) * 16 + l16;
      bp[j] = qkvw + (size_t)wrow * 256 + lq * 8;
    }
    #pragma unroll
    for (int kk = 0; kk < 8; ++kk) {
      bf16x8 af[4];
      #pragma unroll
      for (int m = 0; m < 4; ++m) {
        const int r = m * 16 + l16;
        af[m] = *(const bf16x8*)(smem + OFF_XW + r * 512 + SWZ(r, kk * 64 + lq * 16));
      }
      #pragma unroll
      for (int j = 0; j < 3; ++j) {
        bf16x8 bf = *(const bf16x8*)(bp[j] + kk * 32);
        #pragma unroll
        for (int m = 0; m < 4; ++m)
          acc[m][j] = MFMA16(af[m], bf, acc[m][j]);
      }
    }
    // scatter QKV to LDS (q pre-scaled; v transposed)
    #pragma unroll
    for (int j = 0; j < 3; ++j) {
      const int n = wave * 3 + j;
      const int ty = n >> 3, rem = n & 7;
      const int hh = rem >> 1, half = rem & 1;
      const int d = half * 16 + l16;
      if (ty == 2) {
        #pragma unroll
        for (int m = 0; m < 4; ++m) {
          ushort4 pk;
          pk.x = f2bf(acc[m][j][0]); pk.y = f2bf(acc[m][j][1]);
          pk.z = f2bf(acc[m][j][2]); pk.w = f2bf(acc[m][j][3]);
          const int tok0 = m * 16 + lq * 4;
          *(ushort4*)(smem + OFF_VT + (hh * 32 + d) * 128 + SWZ(d, tok0 * 2)) = pk;
        }
      } else {
        #pragma unroll
        for (int m = 0; m < 4; ++m)
          #pragma unroll
          for (int rr = 0; rr < 4; ++rr) {
            const int tok = m * 16 + lq * 4 + rr;
            const float v = acc[m][j][rr];
            if (ty == 0)
              *(ushort*)(smem + OFF_QK + (hh * 64 + tok) * 128 + SWZ(tok, d * 2)) = f2bf(v * scale);
            else
              *(ushort*)(smem + OFF_QK + (hh * 64 + tok) * 128 + SWZ(tok, 64 + d * 2)) = f2bf(v);
          }
      }
    }
    __syncthreads();  // (b) q/k/vT ready

    // ---- S = Qs*K^T (wave owns head hl, rows [mh*32,+32))
    f32x4 s[2][4];
    {
      bf16x8 qf[2];
      #pragma unroll
      for (int mt = 0; mt < 2; ++mt) {
        const int r = mh * 32 + mt * 16 + l16;
        qf[mt] = *(const bf16x8*)(smem + OFF_QK + (hl * 64 + r) * 128 + SWZ(r, lq * 16));
      }
      #pragma unroll
      for (int nt = 0; nt < 4; ++nt) {
        const int r = nt * 16 + l16;
        bf16x8 kf = *(const bf16x8*)(smem + OFF_QK + (hl * 64 + r) * 128 + SWZ(r, 64 + lq * 16));
        #pragma unroll
        for (int mt = 0; mt < 2; ++mt)
          s[mt][nt] = MFMA16(qf[mt], kf, (f32x4{0.f, 0.f, 0.f, 0.f}));
      }
    }
    __syncthreads();  // (b2) q/k reads done -> P overlays q/k

    // ---- softmax
    const float* biasb = rel_bias + (size_t)(H0 + hl) * 4096;
    float rcp_[2][4];
    #pragma unroll
    for (int mt = 0; mt < 2; ++mt) {
      #pragma unroll
      for (int rr = 0; rr < 4; ++rr) {
        const int qrow = mh * 32 + mt * 16 + lq * 4 + rr;
        float vmax = -1e30f;
        #pragma unroll
        for (int nt = 0; nt < 4; ++nt) {
          float v = s[mt][nt][rr] + biasb[qrow * 64 + nt * 16 + l16];
          s[mt][nt][rr] = v;
          vmax = fmaxf(vmax, v);
        }
        vmax = fmaxf(vmax, __shfl_xor(vmax, 1));
        vmax = fmaxf(vmax, __shfl_xor(vmax, 2));
        vmax = fmaxf(vmax, __shfl_xor(vmax, 4));
        vmax = fmaxf(vmax, __shfl_xor(vmax, 8));
        float ssum = 0.f;
        #pragma unroll
        for (int nt = 0; nt < 4; ++nt) {
          float e = __expf(s[mt][nt][rr] - vmax);
          ssum += e;
          *(ushort*)(smem + OFF_QK + (hl * 64 + qrow) * 128 + SWZ(qrow, (nt * 16 + l16) * 2)) = f2bf(e);
        }
        ssum += __shfl_xor(ssum, 1);
        ssum += __shfl_xor(ssum, 2);
        ssum += __shfl_xor(ssum, 4);
        ssum += __shfl_xor(ssum, 8);
        rcp_[mt][rr] = 1.f / ssum;
      }
    }

    // ---- PV
    f32x4 o[2][2];
    #pragma unroll
    for (int mt = 0; mt < 2; ++mt)
      #pragma unroll
      for (int nt = 0; nt < 2; ++nt)
        o[mt][nt] = f32x4{0.f, 0.f, 0.f, 0.f};
    #pragma unroll
    for (int kk = 0; kk < 2; ++kk) {
      bf16x8 pf[2];
      #pragma unroll
      for (int mt = 0; mt < 2; ++mt) {
        const int r = mh * 32 + mt * 16 + l16;
        pf[mt] = *(const bf16x8*)(smem + OFF_QK + (hl * 64 + r) * 128 + SWZ(r, kk * 64 + lq * 16));
      }
      #pragma unroll
      for (int nt = 0; nt < 2; ++nt) {
        const int r = nt * 16 + l16;
        bf16x8 vf = *(const bf16x8*)(smem + OFF_VT + (hl * 32 + r) * 128 + SWZ(r, kk * 64 + lq * 16));
        #pragma unroll
        for (int mt = 0; mt < 2; ++mt)
          o[mt][nt] = MFMA16(pf[mt], vf, o[mt][nt]);
      }
    }
    __syncthreads();  // (c1) vT reads done -> O tile overlays vt

    #pragma unroll
    for (int mt = 0; mt < 2; ++mt)
      #pragma unroll
      for (int nt = 0; nt < 2; ++nt)
        #pragma unroll
        for (int rr = 0; rr < 4; ++rr) {
          const int tok = mh * 32 + mt * 16 + lq * 4 + rr;
          const int col = hl * 32 + nt * 16 + l16;  // local channel in quad
          *(ushort*)(smem + OFF_VT + tok * 256 + SWZ(tok, col * 2)) = f2bf(o[mt][nt][rr] * rcp_[mt][rr]);
        }
    __syncthreads();  // (c2) O tile ready

    // ---- coalesced O store: [64 tok][128 ch] bf16 -> obuf
    char* od = obuf + (size_t)wid * 32768 + quad * 16384;
    #pragma unroll
    for (int i = 0; i < 2; ++i) {
      const int idx = i * 512 + tid;
      const int row = idx >> 4, c16 = idx & 15;
      bf16x8 v = *(const bf16x8*)(smem + OFF_VT + row * 256 + SWZ(row, c16 * 16));
      *(bf16x8*)(od + row * 256 + c16 * 16) = v;
    }
  }
}

// ============================ split path: kernel B ============================
// out = O @ projW^T + b, with unpad scatter. Streaming GEMM.
// Epilogue stages each wave's 64x32 f32 slab in LDS (stride 34 floats:
// <=2-way banks on write) then stores float2/lane -> 128-B segments.
__global__ __launch_bounds__(256, 4)
void proj_kernel(const char* __restrict__ obuf,     // [8192][2][64][128] bf16
                 const ushort* __restrict__ projw,  // [256][256] bf16
                 const float* __restrict__ proj_b,
                 float* __restrict__ out) {
  __shared__ float slab[4][64][34];
  const int wid = blockIdx.x;
  const int bb_ = wid >> 10;
  const int wy  = (wid >> 5) & 31;
  const int wx  = wid & 31;
  const int tid  = threadIdx.x;
  const int wave = tid >> 6;           // 0..3, owns cols [wave*64, +64)
  const int lane = tid & 63;
  const int l16  = lane & 15;
  const int lq   = lane >> 4;
  const char* ob = obuf + (size_t)wid * 32768;

  #pragma unroll
  for (int half = 0; half < 2; ++half) {
    f32x4 acc[4][2];
    #pragma unroll
    for (int m = 0; m < 4; ++m)
      #pragma unroll
      for (int nt = 0; nt < 2; ++nt)
        acc[m][nt] = f32x4{0.f, 0.f, 0.f, 0.f};

    #pragma unroll
    for (int quad = 0; quad < 2; ++quad)
      #pragma unroll
      for (int kk = 0; kk < 4; ++kk) {
        bf16x8 af[4];
        #pragma unroll
        for (int m = 0; m < 4; ++m)
          af[m] = *(const bf16x8*)(ob + quad * 16384 + (m * 16 + l16) * 256 + kk * 64 + lq * 16);
        #pragma unroll
        for (int nt = 0; nt < 2; ++nt) {
          const int c = wave * 64 + half * 32 + nt * 16 + l16;
          bf16x8 bfr = *(const bf16x8*)(projw + (size_t)c * 256 + quad * 128 + kk * 32 + lq * 8);
          #pragma unroll
          for (int m = 0; m < 4; ++m)
            acc[m][nt] = MFMA16(af[m], bfr, acc[m][nt]);
        }
      }

    // +bias, stage to per-wave LDS slab
    #pragma unroll
    for (int nt = 0; nt < 2; ++nt) {
      const float pb = proj_b[wave * 64 + half * 32 + nt * 16 + l16];
      #pragma unroll
      for (int m = 0; m < 4; ++m)
        #pragma unroll
        for (int rr = 0; rr < 4; ++rr)
          slab[wave][m * 16 + lq * 4 + rr][nt * 16 + l16] = acc[m][nt][rr] + pb;
    }
    __syncthreads();
    // coalesced stores: 16 lanes x float2 = 128-B contiguous segments
    const int colbase = wave * 64 + half * 32;
    #pragma unroll
    for (int it = 0; it < 16; ++it) {
      const int row = it * 4 + lq;
      const int gr = wy * 8 + (row >> 3);
      const int gc = wx * 8 + (row & 7);
      if (gr < 250 && gc < 250) {
        float2 v = *(const float2*)&slab[wave][row][l16 * 2];
        *(float2*)(out + ((size_t)bb_ * 62500 + (size_t)gr * 250 + gc) * 256 + colbase + l16 * 2) = v;
      }
    }
    __syncthreads();
  }
}

// ===================== fallback: Round-3 fused kernel (known-pass) ============
__global__ __launch_bounds__(512, 2)
void swin_fused_kernel(const float* __restrict__ x,
                       const ushort* __restrict__ qkvw,
                       const ushort* __restrict__ projw,
                       const float* __restrict__ proj_b,
                       const float* __restrict__ rel_bias,
                       float* __restrict__ out) {
  extern __shared__ char smem[];
  const int wid = blockIdx.x;
  const int bb_ = wid >> 10;
  const int wy  = (wid >> 5) & 31;
  const int wx  = wid & 31;
  const int tid  = threadIdx.x;
  const int wave = tid >> 6;
  const int lane = tid & 63;
  const int l16  = lane & 15;
  const int lq   = lane >> 4;

  #pragma unroll
  for (int it = 0; it < 8; ++it) {
    const int t  = it * 8 + wave;
    const int gr = wy * 8 + (t >> 3);
    const int gc = wx * 8 + (t & 7);
    float4 v = make_float4(0.f, 0.f, 0.f, 0.f);
    if (gr < 250 && gc < 250)
      v = *(const float4*)(x + ((size_t)bb_ * 62500 + (size_t)gr * 250 + gc) * 256 + lane * 4);
    ushort4 bv;
    bv.x = f2bf(v.x); bv.y = f2bf(v.y); bv.z = f2bf(v.z); bv.w = f2bf(v.w);
    *(ushort4*)(smem + OFF_XW + t * 512 + SWZ(t, lane * 8)) = bv;
  }

  f32x4 oacc[4][2];
  #pragma unroll
  for (int m = 0; m < 4; ++m)
    #pragma unroll
    for (int n = 0; n < 2; ++n)
      oacc[m][n] = f32x4{0.f, 0.f, 0.f, 0.f};

  const int hl = wave >> 1;
  const int mh = wave & 1;
  const float scale = 0.17677669529663687f;

  for (int quad = 0; quad < 2; ++quad) {
    const int H0 = quad * 4;
    __syncthreads();
    f32x4 acc[4][3];
    #pragma unroll
    for (int m = 0; m < 4; ++m)
      #pragma unroll
      for (int j = 0; j < 3; ++j)
        acc[m][j] = f32x4{0.f, 0.f, 0.f, 0.f};
    const ushort* bp[3];
    #pragma unroll
    for (int j = 0; j < 3; ++j) {
      const int n = wave * 3 + j;
      const int ty = n >> 3, rem = n & 7;
      const int wrow = ty * 256 + (H0 + (rem >> 1)) * 32 + (rem & 1) * 16 + l16;
      bp[j] = qkvw + (size_t)wrow * 256 + lq * 8;
    }
    #pragma unroll
    for (int kk = 0; kk < 8; ++kk) {
      bf16x8 af[4];
      #pragma unroll
      for (int m = 0; m < 4; ++m) {
        const int r = m * 16 + l16;
        af[m] = *(const bf16x8*)(smem + OFF_XW + r * 512 + SWZ(r, kk * 64 + lq * 16));
      }
      #pragma unroll
      for (int j = 0; j < 3; ++j) {
        bf16x8 bf = *(const bf16x8*)(bp[j] + kk * 32);
        #pragma unroll
        for (int m = 0; m < 4; ++m)
          acc[m][j] = MFMA16(af[m], bf, acc[m][j]);
      }
    }
    #pragma unroll
    for (int j = 0; j < 3; ++j) {
      const int n = wave * 3 + j;
      const int ty = n >> 3, rem = n & 7;
      const int hh = rem >> 1, half = rem & 1;
      const int d = half * 16 + l16;
      if (ty == 2) {
        #pragma unroll
        for (int m = 0; m < 4; ++m) {
          ushort4 pk;
          pk.x = f2bf(acc[m][j][0]); pk.y = f2bf(acc[m][j][1]);
          pk.z = f2bf(acc[m][j][2]); pk.w = f2bf(acc[m][j][3]);
          const int tok0 = m * 16 + lq * 4;
          *(ushort4*)(smem + OFF_VT + (hh * 32 + d) * 128 + SWZ(d, tok0 * 2)) = pk;
        }
      } else {
        #pragma unroll
        for (int m = 0; m < 4; ++m)
          #pragma unroll
          for (int rr = 0; rr < 4; ++rr) {
            const int tok = m * 16 + lq * 4 + rr;
            const float v = acc[m][j][rr];
            if (ty == 0)
              *(ushort*)(smem + OFF_QK + (hh * 64 + tok) * 128 + SWZ(tok, d * 2)) = f2bf(v * scale);
            else
              *(ushort*)(smem + OFF_QK + (hh * 64 + tok) * 128 + SWZ(tok, 64 + d * 2)) = f2bf(v);
          }
      }
    }
    __syncthreads();
    f32x4 s[2][4];
    {
      bf16x8 qf[2];
      #pragma unroll
      for (int mt = 0; mt < 2; ++mt) {
        const int r = mh * 32 + mt * 16 + l16;
        qf[mt] = *(const bf16x8*)(smem + OFF_QK + (hl * 64 + r) * 128 + SWZ(r, lq * 16));
      }
      #pragma unroll
      for (int nt = 0; nt < 4; ++nt) {
        const int r = nt * 16 + l16;
        bf16x8 kf = *(const bf16x8*)(smem + OFF_QK + (hl * 64 + r) * 128 + SWZ(r, 64 + lq * 16));
        #pragma unroll
        for (int mt = 0; mt < 2; ++mt)
          s[mt][nt] = MFMA16(qf[mt], kf, (f32x4{0.f, 0.f, 0.f, 0.f}));
      }
    }
    __syncthreads();
    const float* biasb = rel_bias + (size_t)(H0 + hl) * 4096;
    float rcp_[2][4];
    #pragma unroll
    for (int mt = 0; mt < 2; ++mt) {
      #pragma unroll
      for (int rr = 0; rr < 4; ++rr) {
        const int qrow = mh * 32 + mt * 16 + lq * 4 + rr;
        float vmax = -1e30f;
        #pragma unroll
        for (int nt = 0; nt < 4; ++nt) {
          float v = s[mt][nt][rr] + biasb[qrow * 64 + nt * 16 + l16];
          s[mt][nt][rr] = v;
          vmax = fmaxf(vmax, v);
        }
        vmax = fmaxf(vmax, __shfl_xor(vmax, 1));
        vmax = fmaxf(vmax, __shfl_xor(vmax, 2));
        vmax = fmaxf(vmax, __shfl_xor(vmax, 4));
        vmax = fmaxf(vmax, __shfl_xor(vmax, 8));
        float ssum = 0.f;
        #pragma unroll
        for (int nt = 0; nt < 4; ++nt) {
          float e = __expf(s[mt][nt][rr] - vmax);
          ssum += e;
          *(ushort*)(smem + OFF_QK + (hl * 64 + qrow) * 128 + SWZ(qrow, (nt * 16 + l16) * 2)) = f2bf(e);
        }
        ssum += __shfl_xor(ssum, 1);
        ssum += __shfl_xor(ssum, 2);
        ssum += __shfl_xor(ssum, 4);
        ssum += __shfl_xor(ssum, 8);
        rcp_[mt][rr] = 1.f / ssum;
      }
    }
    f32x4 o[2][2];
    #pragma unroll
    for (int mt = 0; mt < 2; ++mt)
      #pragma unroll
      for (int nt = 0; nt < 2; ++nt)
        o[mt][nt] = f32x4{0.f, 0.f, 0.f, 0.f};
    #pragma unroll
    for (int kk = 0; kk < 2; ++kk) {
      bf16x8 pf[2];
      #pragma unroll
      for (int mt = 0; mt < 2; ++mt) {
        const int r = mh * 32 + mt * 16 + l16;
        pf[mt] = *(const bf16x8*)(smem + OFF_QK + (hl * 64 + r) * 128 + SWZ(r, kk * 64 + lq * 16));
      }
      #pragma unroll
      for (int nt = 0; nt < 2; ++nt) {
        const int r = nt * 16 + l16;
        bf16x8 vf = *(const bf16x8*)(smem + OFF_VT + (hl * 32 + r) * 128 + SWZ(r, kk * 64 + lq * 16));
        #pragma unroll
        for (int mt = 0; mt < 2; ++mt)
          o[mt][nt] = MFMA16(pf[mt], vf, o[mt][nt]);
      }
    }
    __syncthreads();
    #pragma unroll
    for (int mt = 0; mt < 2; ++mt)
      #pragma unroll
      for (int nt = 0; nt < 2; ++nt)
        #pragma unroll
        for (int rr = 0; rr < 4; ++rr) {
          const int tok = mh * 32 + mt * 16 + lq * 4 + rr;
          const int col = hl * 32 + nt * 16 + l16;
          *(ushort*)(smem + OFF_VT + tok * 256 + SWZ(tok, col * 2)) = f2bf(o[mt][nt][rr] * rcp_[mt][rr]);
        }
    __syncthreads();
    #pragma unroll
    for (int kk = 0; kk < 4; ++kk) {
      bf16x8 af[4];
      #pragma unroll
      for (int m = 0; m < 4; ++m) {
        const int r = m * 16 + l16;
        af[m] = *(const bf16x8*)(smem + OFF_VT + r * 256 + SWZ(r, kk * 64 + lq * 16));
      }
      #pragma unroll
      for (int nt = 0; nt < 2; ++nt) {
        const int c = wave * 32 + nt * 16 + l16;
        bf16x8 bfr = *(const bf16x8*)(projw + (size_t)c * 256 + quad * 128 + kk * 32 + lq * 8);
        #pragma unroll
        for (int m = 0; m < 4; ++m)
          oacc[m][nt] = MFMA16(af[m], bfr, oacc[m][nt]);
      }
    }
  }

  __syncthreads();
  #pragma unroll
  for (int nt = 0; nt < 2; ++nt) {
    const int col = wave * 32 + nt * 16 + l16;
    const float pb = proj_b[col];
    #pragma unroll
    for (int m = 0; m < 4; ++m)
      #pragma unroll
      for (int rr = 0; rr < 4; ++rr) {
        const int row = m * 16 + lq * 4 + rr;
        *(float*)(smem + row * 1024 + SWZ(row, col * 4)) = oacc[m][nt][rr] + pb;
      }
  }
  __syncthreads();
  #pragma unroll
  for (int it = 0; it < 8; ++it) {
    const int t  = it * 8 + wave;
    const int gr = wy * 8 + (t >> 3);
    const int gc = wx * 8 + (t & 7);
    if (gr < 250 && gc < 250) {
      float4 v = *(const float4*)(smem + t * 1024 + SWZ(t, lane * 16));
      *(float4*)(out + ((size_t)bb_ * 62500 + (size_t)gr * 250 + gc) * 256 + lane * 4) = v;
    }
  }
}

extern "C" void kernel_launch(void* const* d_in, const int* in_sizes, int n_in,
                              void* d_out, int out_size, void* d_ws, size_t ws_size,
                              hipStream_t stream) {
  const float* x        = (const float*)d_in[0];
  const float* qkv_w    = (const float*)d_in[1];
  const float* proj_w   = (const float*)d_in[2];
  const float* proj_b   = (const float*)d_in[3];
  const float* rel_bias = (const float*)d_in[4];
  float* out = (float*)d_out;
  ushort* wsb = (ushort*)d_ws;

  (void)in_sizes; (void)n_in; (void)out_size;

  hipFuncSetAttribute((const void*)swin_attn_kernel,
                      hipFuncAttributeMaxDynamicSharedMemorySize, LDS_TOTAL);
  hipFuncSetAttribute((const void*)swin_fused_kernel,
                      hipFuncAttributeMaxDynamicSharedMemorySize, LDS_TOTAL);

  convert_w_kernel<<<1024, 256, 0, stream>>>(qkv_w, proj_w, wsb);

  if (ws_size >= WS_NEED) {
    char* obuf = (char*)d_ws + OBUF_OFF;
    swin_attn_kernel<<<8192, 512, LDS_TOTAL, stream>>>(x, wsb, rel_bias, obuf);
    proj_kernel<<<8192, 256, 0, stream>>>(obuf, wsb + NQKV, proj_b, out);
  } else {
    swin_fused_kernel<<<8192, 512, LDS_TOTAL, stream>>>(x, wsb, wsb + NQKV, proj_b,
                                                        rel_bias, out);
  }
}

// Round 6
// 971.507 us; speedup vs baseline: 2.5655x; 1.8161x over previous
//
#include <hip/hip_runtime.h>
#include <hip/hip_bf16.h>

typedef short bf16x8 __attribute__((ext_vector_type(8)));
typedef float f32x4 __attribute__((ext_vector_type(4)));

#define MFMA16(A,B,C) __builtin_amdgcn_mfma_f32_16x16x32_bf16(A,B,C,0,0,0)

static __device__ __forceinline__ unsigned short f2bf(float f) {
  unsigned int u = __float_as_uint(f);
  u += 0x7fffu + ((u >> 16) & 1u);        // round-to-nearest-even
  return (unsigned short)(u >> 16);
}

// ---- LDS layout (bytes), 80 KB total -> 2 blocks/CU (needs regs <=128/wave too).
// xw  [64 rows][512 B]      : x window bf16, XOR-swizzled
// qk  [4h][64 rows][128 B]  : q cols 0..31, k cols 32..63 ; overlaid by P
// vt  [4h][32 rows(d)][128 B (64 toks)] ; overlaid by o4 [64 rows][256 B]
// epilogue reuses bytes [0, 65536) as f32 [64][256] out tile
#define SWZ(row, byte) ((byte) ^ (((row) & 7) << 4))
#define OFF_XW 0
#define OFF_QK 32768
#define OFF_VT 65536
#define LDS_TOTAL 81920

#define NQKV 196608   // 768*256
#define NPROJ 65536   // 256*256

__global__ void convert_w_kernel(const float* __restrict__ qkv_w,
                                 const float* __restrict__ proj_w,
                                 ushort* __restrict__ wsb) {
  int i = blockIdx.x * 256 + threadIdx.x;
  if (i < NQKV) wsb[i] = f2bf(qkv_w[i]);
  else if (i < NQKV + NPROJ) wsb[i] = f2bf(proj_w[i - NQKV]);
}

// Register-diet fused kernel.
// R1 (monolith, acc[4][3]) = 100 VGPR no spill but 147KB LDS -> 1 blk/CU.
// R3 (swizzled, acc[4][3]) = 128 VGPR PINNED + spill -> 1 blk/CU.
// Here: QKV n-tiles processed SEQUENTIALLY (#pragma unroll 1, acc[4] inside the
// loop body -> static indexing, 16 accum regs instead of 48). Target: true
// VGPR <=~115 -> no spill, 2 blocks/CU from the 80 KB LDS cap.
__global__ __launch_bounds__(512, 2)
void swin_fused_kernel(const float* __restrict__ x,
                       const ushort* __restrict__ qkvw,   // [768][256] bf16
                       const ushort* __restrict__ projw,  // [256][256] bf16
                       const float* __restrict__ proj_b,
                       const float* __restrict__ rel_bias, // [8][64][64] f32
                       float* __restrict__ out) {
  extern __shared__ char smem[];

  const int wid = blockIdx.x;          // window id 0..8191
  const int bb_ = wid >> 10;           // batch
  const int wy  = (wid >> 5) & 31;
  const int wx  = wid & 31;
  const int tid  = threadIdx.x;
  const int wave = tid >> 6;           // 0..7
  const int lane = tid & 63;
  const int l16  = lane & 15;
  const int lq   = lane >> 4;          // 0..3

  // ---- phase 0: stage x window [64 tokens][256 ch] as bf16 (zero-fill padding)
  #pragma unroll
  for (int it = 0; it < 8; ++it) {
    const int t  = it * 8 + wave;
    const int gr = wy * 8 + (t >> 3);
    const int gc = wx * 8 + (t & 7);
    float4 v = make_float4(0.f, 0.f, 0.f, 0.f);
    if (gr < 250 && gc < 250)
      v = *(const float4*)(x + ((size_t)bb_ * 62500 + (size_t)gr * 250 + gc) * 256 + lane * 4);
    ushort4 bv;
    bv.x = f2bf(v.x); bv.y = f2bf(v.y); bv.z = f2bf(v.z); bv.w = f2bf(v.w);
    *(ushort4*)(smem + OFF_XW + t * 512 + SWZ(t, lane * 8)) = bv;
  }

  f32x4 oacc[4][2];                    // persistent proj accumulator
  #pragma unroll
  for (int m = 0; m < 4; ++m)
    #pragma unroll
    for (int n = 0; n < 2; ++n)
      oacc[m][n] = f32x4{0.f, 0.f, 0.f, 0.f};

  const int hl = wave >> 1;            // local head 0..3
  const int mh = wave & 1;             // row-half
  const float scale = 0.17677669529663687f;  // 32^-0.5

  #pragma unroll 1
  for (int quad = 0; quad < 2; ++quad) {
    const int H0 = quad * 4;
    __syncthreads();  // (a) xw ready / previous quad's proj done with o4 region

    // ---- QKV GEMM: [64,256] x [256, 4heads*96]; 24 n-tiles, wave owns 3,
    // processed SEQUENTIALLY to keep accumulator pressure at acc[4] (16 regs).
    #pragma unroll 1
    for (int j = 0; j < 3; ++j) {
      const int n = wave * 3 + j;
      const int ty = n >> 3, rem = n & 7;
      const int hh = rem >> 1, half = rem & 1;
      const int wrow = ty * 256 + (H0 + hh) * 32 + half * 16 + l16;
      const ushort* bp = qkvw + (size_t)wrow * 256 + lq * 8;

      f32x4 acc[4];
      #pragma unroll
      for (int m = 0; m < 4; ++m) acc[m] = f32x4{0.f, 0.f, 0.f, 0.f};

      #pragma unroll
      for (int kk = 0; kk < 8; ++kk) {
        bf16x8 bf = *(const bf16x8*)(bp + kk * 32);
        #pragma unroll
        for (int m = 0; m < 4; ++m) {
          const int r = m * 16 + l16;
          bf16x8 af = *(const bf16x8*)(smem + OFF_XW + r * 512 + SWZ(r, kk * 64 + lq * 16));
          acc[m] = MFMA16(af, bf, acc[m]);
        }
      }
      // scatter to LDS (q pre-scaled; v transposed)
      const int d = half * 16 + l16;
      if (ty == 2) {
        #pragma unroll
        for (int m = 0; m < 4; ++m) {
          ushort4 pk;
          pk.x = f2bf(acc[m][0]); pk.y = f2bf(acc[m][1]);
          pk.z = f2bf(acc[m][2]); pk.w = f2bf(acc[m][3]);
          const int tok0 = m * 16 + lq * 4;
          *(ushort4*)(smem + OFF_VT + (hh * 32 + d) * 128 + SWZ(d, tok0 * 2)) = pk;
        }
      } else if (ty == 0) {
        #pragma unroll
        for (int m = 0; m < 4; ++m)
          #pragma unroll
          for (int rr = 0; rr < 4; ++rr) {
            const int tok = m * 16 + lq * 4 + rr;
            *(ushort*)(smem + OFF_QK + (hh * 64 + tok) * 128 + SWZ(tok, d * 2)) = f2bf(acc[m][rr] * scale);
          }
      } else {
        #pragma unroll
        for (int m = 0; m < 4; ++m)
          #pragma unroll
          for (int rr = 0; rr < 4; ++rr) {
            const int tok = m * 16 + lq * 4 + rr;
            *(ushort*)(smem + OFF_QK + (hh * 64 + tok) * 128 + SWZ(tok, 64 + d * 2)) = f2bf(acc[m][rr]);
          }
      }
    }
    __syncthreads();  // (b) q/k/vT ready

    // ---- S = Qs*K^T (wave owns head hl, rows [mh*32,+32))
    f32x4 s[2][4];
    {
      bf16x8 qf[2];
      #pragma unroll
      for (int mt = 0; mt < 2; ++mt) {
        const int r = mh * 32 + mt * 16 + l16;
        qf[mt] = *(const bf16x8*)(smem + OFF_QK + (hl * 64 + r) * 128 + SWZ(r, lq * 16));
      }
      #pragma unroll
      for (int nt = 0; nt < 4; ++nt) {
        const int r = nt * 16 + l16;
        bf16x8 kf = *(const bf16x8*)(smem + OFF_QK + (hl * 64 + r) * 128 + SWZ(r, 64 + lq * 16));
        #pragma unroll
        for (int mt = 0; mt < 2; ++mt)
          s[mt][nt] = MFMA16(qf[mt], kf, (f32x4{0.f, 0.f, 0.f, 0.f}));
      }
    }
    __syncthreads();  // (b2) all q/k reads done -> P may overlay q/k

    // ---- softmax (P into q/k region)
    const float* biasb = rel_bias + (size_t)(H0 + hl) * 4096;
    float rcp_[2][4];
    #pragma unroll
    for (int mt = 0; mt < 2; ++mt) {
      #pragma unroll
      for (int rr = 0; rr < 4; ++rr) {
        const int qrow = mh * 32 + mt * 16 + lq * 4 + rr;
        float vmax = -1e30f;
        #pragma unroll
        for (int nt = 0; nt < 4; ++nt) {
          float v = s[mt][nt][rr] + biasb[qrow * 64 + nt * 16 + l16];
          s[mt][nt][rr] = v;
          vmax = fmaxf(vmax, v);
        }
        vmax = fmaxf(vmax, __shfl_xor(vmax, 1));
        vmax = fmaxf(vmax, __shfl_xor(vmax, 2));
        vmax = fmaxf(vmax, __shfl_xor(vmax, 4));
        vmax = fmaxf(vmax, __shfl_xor(vmax, 8));
        float ssum = 0.f;
        #pragma unroll
        for (int nt = 0; nt < 4; ++nt) {
          float e = __expf(s[mt][nt][rr] - vmax);
          ssum += e;
          *(ushort*)(smem + OFF_QK + (hl * 64 + qrow) * 128 + SWZ(qrow, (nt * 16 + l16) * 2)) = f2bf(e);
        }
        ssum += __shfl_xor(ssum, 1);
        ssum += __shfl_xor(ssum, 2);
        ssum += __shfl_xor(ssum, 4);
        ssum += __shfl_xor(ssum, 8);
        rcp_[mt][rr] = 1.f / ssum;
      }
    }

    // ---- PV: O[32 rows][32 d] per wave
    f32x4 o[2][2];
    #pragma unroll
    for (int mt = 0; mt < 2; ++mt)
      #pragma unroll
      for (int nt = 0; nt < 2; ++nt)
        o[mt][nt] = f32x4{0.f, 0.f, 0.f, 0.f};
    #pragma unroll
    for (int kk = 0; kk < 2; ++kk) {
      bf16x8 pf[2];
      #pragma unroll
      for (int mt = 0; mt < 2; ++mt) {
        const int r = mh * 32 + mt * 16 + l16;
        pf[mt] = *(const bf16x8*)(smem + OFF_QK + (hl * 64 + r) * 128 + SWZ(r, kk * 64 + lq * 16));
      }
      #pragma unroll
      for (int nt = 0; nt < 2; ++nt) {
        const int r = nt * 16 + l16;
        bf16x8 vf = *(const bf16x8*)(smem + OFF_VT + (hl * 32 + r) * 128 + SWZ(r, kk * 64 + lq * 16));
        #pragma unroll
        for (int mt = 0; mt < 2; ++mt)
          o[mt][nt] = MFMA16(pf[mt], vf, o[mt][nt]);
      }
    }
    __syncthreads();  // (c1) all vT reads done -> o4 may overlay vt

    #pragma unroll
    for (int mt = 0; mt < 2; ++mt)
      #pragma unroll
      for (int nt = 0; nt < 2; ++nt)
        #pragma unroll
        for (int rr = 0; rr < 4; ++rr) {
          const int tok = mh * 32 + mt * 16 + lq * 4 + rr;
          const int col = hl * 32 + nt * 16 + l16;
          *(ushort*)(smem + OFF_VT + tok * 256 + SWZ(tok, col * 2)) = f2bf(o[mt][nt][rr] * rcp_[mt][rr]);
        }
    __syncthreads();  // (c2) o4 ready

    // ---- proj partial: oacc += O4[64, quad*128..+128] x projW^T slice
    #pragma unroll
    for (int kk = 0; kk < 4; ++kk) {
      bf16x8 af[4];
      #pragma unroll
      for (int m = 0; m < 4; ++m) {
        const int r = m * 16 + l16;
        af[m] = *(const bf16x8*)(smem + OFF_VT + r * 256 + SWZ(r, kk * 64 + lq * 16));
      }
      #pragma unroll
      for (int nt = 0; nt < 2; ++nt) {
        const int c = wave * 32 + nt * 16 + l16;
        bf16x8 bfr = *(const bf16x8*)(projw + (size_t)c * 256 + quad * 128 + kk * 32 + lq * 8);
        #pragma unroll
        for (int m = 0; m < 4; ++m)
          oacc[m][nt] = MFMA16(af[m], bfr, oacc[m][nt]);
      }
    }
  }  // quad

  // ---- epilogue: +proj_b, transpose through LDS, coalesced float4 stores
  __syncthreads();  // all P/o4 reads done -> reuse bytes [0,65536) as f32 tile
  #pragma unroll
  for (int nt = 0; nt < 2; ++nt) {
    const int col = wave * 32 + nt * 16 + l16;
    const float pb = proj_b[col];
    #pragma unroll
    for (int m = 0; m < 4; ++m)
      #pragma unroll
      for (int rr = 0; rr < 4; ++rr) {
        const int row = m * 16 + lq * 4 + rr;
        *(float*)(smem + row * 1024 + SWZ(row, col * 4)) = oacc[m][nt][rr] + pb;
      }
  }
  __syncthreads();
  #pragma unroll
  for (int it = 0; it < 8; ++it) {
    const int t  = it * 8 + wave;
    const int gr = wy * 8 + (t >> 3);
    const int gc = wx * 8 + (t & 7);
    if (gr < 250 && gc < 250) {
      float4 v = *(const float4*)(smem + t * 1024 + SWZ(t, lane * 16));
      *(float4*)(out + ((size_t)bb_ * 62500 + (size_t)gr * 250 + gc) * 256 + lane * 4) = v;
    }
  }
}

extern "C" void kernel_launch(void* const* d_in, const int* in_sizes, int n_in,
                              void* d_out, int out_size, void* d_ws, size_t ws_size,
                              hipStream_t stream) {
  const float* x        = (const float*)d_in[0];
  const float* qkv_w    = (const float*)d_in[1];
  const float* proj_w   = (const float*)d_in[2];
  const float* proj_b   = (const float*)d_in[3];
  const float* rel_bias = (const float*)d_in[4];
  float* out = (float*)d_out;
  ushort* wsb = (ushort*)d_ws;  // [0,196608): qkv_w bf16; [196608,262144): proj_w bf16

  (void)in_sizes; (void)n_in; (void)out_size; (void)ws_size;

  hipFuncSetAttribute((const void*)swin_fused_kernel,
                      hipFuncAttributeMaxDynamicSharedMemorySize, LDS_TOTAL);

  convert_w_kernel<<<1024, 256, 0, stream>>>(qkv_w, proj_w, wsb);
  swin_fused_kernel<<<8192, 512, LDS_TOTAL, stream>>>(x, wsb, wsb + NQKV, proj_b,
                                                      rel_bias, out);
}